// Round 16
// baseline (384.110 us; speedup 1.0000x reference)
//
#include <hip/hip_runtime.h>
#include <hip/hip_bf16.h>
#include <stdint.h>

// d_out FLOAT32. Layout (f32 elems): nodes [0,4202432) | idx0 [4202432,38675779)
// | idx1 [38675779,73149126) | vals [73149126,107622473)
#define NNZ       34473347LL
#define IDX0_OFF  4202432LL
#define IDX1_OFF  38675779LL
#define VALS_OFF  73149126LL
#define OUT_TOTAL 107622473LL

__constant__ int       cN[9] = {0, 65663, 32831, 16415, 8207, 4103, 2051, 1025, 512};
__constant__ long long cV[9] = {0, 34473347LL, 17171011LL, 8552675LL, 4259923LL,
                                2121755LL, 1056775LL, 526337LL, 262144LL};
__constant__ int       cSZ[8] = {0, 131325, 65661, 32829, 16413, 8205, 4101, 2049};
__constant__ int gD[21] = {2, 3,3, 4,4,4, 5,5,5,5, 6,6,6,6,6, 7,7,7,7,7,7};
__constant__ int gA[21] = {1, 1,2, 1,2,3, 1,2,3,4, 1,2,3,4,5, 1,2,3,4,5,6};
__constant__ int gB[21] = {0, 2,6, 10,18,26, 34,50,66,82, 98,130,162,194,226,
                           258,322,386,450,514,578};

// r16_rest role layout (all LDS-free roles fused)
#define RB_IDXI  4096          // int: [0,4096)
#define RB_NODEL 7694          // idx_int: [4096,7694)  (514*7=3598)
#define RB_MP    11790         // nodeL: [7694,11790)   (4096)
#define RB_ALL   11983         // mp: [11790,11983)     (193)

// ---- launch 1: per-leaf partial column sums (8 partials per leaf) ----
__global__ void r16_sums(const float* __restrict__ X, float* __restrict__ part) {
    __shared__ float sm[4][64];
    int b = blockIdx.x;                       // 1024 = leaf*8 + j
    int t = b >> 3, j = b & 7;
    int k = threadIdx.x & 63, p = threadIdx.x >> 6;
    const float* xp = X + (long long)t * 32768 + (long long)j * 64 * 64;
    float s = 0.f;
    for (int i = p * 16; i < p * 16 + 16; ++i) s += xp[i * 64 + k];
    sm[p][k] = s;
    __syncthreads();
    if (threadIdx.x < 64)
        part[b * 64 + k] = sm[0][k] + sm[1][k] + sm[2][k] + sm[3][k];
}

// ---- launch 2: row norms ----
__global__ void r16_norm(const float* __restrict__ X, float* __restrict__ xn) {
    int w = threadIdx.x >> 6, lane = threadIdx.x & 63;
    long long row = (long long)blockIdx.x * 4 + w;
    float x = X[row * 64 + lane];
    float s = x * x;
    #pragma unroll
    for (int o = 32; o; o >>= 1) s += __shfl_xor(s, o, 64);
    if (lane == 0) xn[row] = s;
}

// ---- launch 3: all 127 means (range-mean identity), node rows, |m|^2 ----
__global__ void r16_means(const float* __restrict__ part, float* __restrict__ means,
                          float* __restrict__ mn2, float* __restrict__ out) {
    int h = blockIdx.x + 1;
    int k = threadIdx.x;
    int d = 32 - __clz(h);
    int t = h - (1 << (d - 1));
    int lo = (t << (8 - d)) * 8, cnt = (1 << (8 - d)) * 8;
    float s = 0.f;
    for (int l = lo; l < lo + cnt; ++l) s += part[l * 64 + k];
    float mv = s / (float)(1 << (17 - d));
    means[blockIdx.x * 64 + k] = mv;
    long long bb = 0;
    for (int jj = 1; jj <= d - 1; ++jj)
        if ((t >> (d - 1 - jj)) & 1) bb += cN[jj + 1];
    out[(bb + cN[d] - 1) * 64 + k] = mv;
    float sq = mv * mv;
    #pragma unroll
    for (int o = 32; o; o >>= 1) sq += __shfl_xor(sq, o, 64);
    if (k == 0) mn2[blockIdx.x] = sq;
}

// ---- launch 4: leaf tiles -> vals + idx0 + idx1 (plain stores) ----
__global__ __launch_bounds__(256) void r16_leaf(const float* __restrict__ X,
                                                const float* __restrict__ xn,
                                                float* __restrict__ out) {
    __shared__ float As[32][128];
    __shared__ float Bs[32][128];
    int bx = blockIdx.x;
    int t = bx >> 4, tile = bx & 15, br = tile >> 2, bc = tile & 3;
    int tid = threadIdx.x;

    long long voff = 0; int nb = 0;
    #pragma unroll
    for (int jj = 1; jj <= 7; ++jj)
        if ((t >> (7 - jj)) & 1) { voff += cV[jj + 1]; nb += cN[jj + 1]; }

    const float* xleaf = X + (long long)t * 32768;

    float acc[8][8] = {};
    for (int ks = 0; ks < 64; ks += 32) {
        __syncthreads();
        #pragma unroll
        for (int u = 0; u < 4; ++u) {
            int idx = tid * 4 + u;
            int i = idx >> 3, k4 = (idx & 7) * 4;
            float4 va = *(const float4*)&xleaf[(long long)(br * 128 + i) * 64 + ks + k4];
            As[k4 + 0][i] = va.x; As[k4 + 1][i] = va.y; As[k4 + 2][i] = va.z; As[k4 + 3][i] = va.w;
            float4 vb = *(const float4*)&xleaf[(long long)(bc * 128 + i) * 64 + ks + k4];
            Bs[k4 + 0][i] = vb.x; Bs[k4 + 1][i] = vb.y; Bs[k4 + 2][i] = vb.z; Bs[k4 + 3][i] = vb.w;
        }
        __syncthreads();
        int ty = tid >> 4, tx = tid & 15;
        for (int k = 0; k < 32; ++k) {
            float a[8], bb[8];
            *(float4*)&a[0]  = *(const float4*)&As[k][ty * 8];
            *(float4*)&a[4]  = *(const float4*)&As[k][ty * 8 + 4];
            *(float4*)&bb[0] = *(const float4*)&Bs[k][tx * 4];
            *(float4*)&bb[4] = *(const float4*)&Bs[k][64 + tx * 4];
            #pragma unroll
            for (int r = 0; r < 8; ++r)
                #pragma unroll
                for (int c = 0; c < 8; ++c) acc[r][c] += a[r] * bb[c];
        }
    }

    int ty = tid >> 4, tx = tid & 15;
    int r0g = br * 128 + ty * 8;
    int cga = bc * 128 + tx * 4;

    float nbv[8], i1v[8];
    #pragma unroll
    for (int c = 0; c < 4; ++c) {
        nbv[c]     = xn[(long long)t * 512 + cga + c];
        nbv[4 + c] = xn[(long long)t * 512 + cga + 64 + c];
        i1v[c]     = (float)(nb + cga + c);
        i1v[4 + c] = (float)(nb + cga + 64 + c);
    }

    #pragma unroll
    for (int r = 0; r < 8; ++r) {
        int grow = r0g + r;
        float nar = xn[(long long)t * 512 + grow];
        float i0f = (float)(nb + grow);
        long long rb = voff + (long long)grow * 512;
        #pragma unroll
        for (int h = 0; h < 2; ++h) {
            long long cb = rb + cga + h * 64;
            #pragma unroll
            for (int c = 0; c < 4; ++c) {
                float d2 = nar + nbv[h * 4 + c] - 2.0f * acc[r][h * 4 + c];
                out[VALS_OFF + cb + c] = __expf(-d2 * 0.015625f);
                out[IDX0_OFF + cb + c] = i0f;
                out[IDX1_OFF + cb + c] = i1v[h * 4 + c];
            }
        }
    }
}

// ---- launch 5: fused LDS-free roles: int | idx_int | nodeL | meanpairs ----
__global__ __launch_bounds__(256) void r16_rest(const float* __restrict__ X,
                                                const float* __restrict__ xn,
                                                const float* __restrict__ means,
                                                const float* __restrict__ mn2,
                                                float* __restrict__ out) {
    int bid = blockIdx.x;
    int tid = threadIdx.x;

    if (bid < RB_IDXI) {
        // ---- internal X-row values (7 ancestors per row) ----
        int lane = tid & 63;
        int wv = (bid << 2) + (tid >> 6);
        for (int it = 0; it < 4; ++it) {
            int r = wv + (it << 14);
            float x = X[(long long)r * 64 + lane];
            float xnr = xn[r];
            int t7 = r >> 9, col = r & 511;
            float mydot = 0.f;
            #pragma unroll
            for (int d = 1; d <= 7; ++d) {
                int h0 = (1 << (d - 1)) + (r >> (17 - d)) - 1;
                float p = x * means[h0 * 64 + lane];
                #pragma unroll
                for (int o = 32; o; o >>= 1) p += __shfl_xor(p, o, 64);
                if (lane == d - 1) mydot = p;
            }
            if (lane < 7) {
                int d = lane + 1;
                int h0 = (1 << (d - 1)) + (r >> (17 - d)) - 1;
                long long voff = 0, q = col;
                #pragma unroll
                for (int jj = 1; jj <= 7; ++jj) {
                    int bit = (t7 >> (7 - jj)) & 1;
                    if (bit) { if (jj < d) voff += cV[jj + 1]; else q += cN[jj + 1]; }
                }
                long long m = cN[d] - 1;
                long long co = voff + 2 * cV[d + 1];
                float v = __expf(-(xnr - 2.0f * mydot + mn2[h0]) * 0.015625f);
                out[VALS_OFF + co + q]     = v;
                out[VALS_OFF + co + m + q] = v;
            }
        }
    } else if (bid < RB_NODEL) {
        // ---- internal-chunk indices ----
        int local = bid - RB_IDXI;
        int d = local / 514 + 1;
        int bx = local % 514;
        int sz = cSZ[d];
        int m = cN[d] - 1;
        long long pos = (long long)bx * 256 + tid;
        long long tot = (long long)(1 << (d - 1)) * sz;
        if (pos < tot) {
            int t = (int)(pos / sz);
            int e = (int)(pos % sz);
            long long voff = 0; long long base = 0;
            for (int jj = 1; jj < d; ++jj)
                if ((t >> (d - 1 - jj)) & 1) { voff += cV[jj + 1]; base += cN[jj + 1]; }
            long long p = voff + 2 * cV[d + 1] + e;
            long long i0, i1;
            if (e < m)          { i0 = base + e;     i1 = base + m; }
            else if (e < 2 * m) { i0 = base + m;     i1 = base + e - m; }
            else                { i0 = base + m;     i1 = base + m; }
            out[IDX0_OFF + p] = (float)i0;
            out[IDX1_OFF + p] = (float)i1;
        }
    } else if (bid < RB_MP) {
        // ---- leaf-node rows ----
        int local = bid - RB_NODEL;
        long long e = ((long long)local * 256 + tid) * 4;
        int t = (int)(e >> 15);
        int l = (int)(e & 32767);
        int j = l >> 6, k = l & 63;
        int b = 0;
        #pragma unroll
        for (int jj = 1; jj <= 7; ++jj) if ((t >> (7 - jj)) & 1) b += cN[jj + 1];
        float4 v = *(const float4*)&X[e];
        *(float4*)&out[((long long)b + j) * 64 + k] = v;
    } else {
        // ---- mean-vs-mean pairs + 1.0 entries ----
        int local = bid - RB_MP;
        int wv = (local << 2) + (tid >> 6);
        int lane = tid & 63;
        if (wv >= 769) return;
        if (wv < 642) {
            int g = 0;
            while (g < 20 && wv >= gB[g + 1]) ++g;
            int dp = gD[g], a = gA[g];
            int tp = wv - gB[g];
            int hp = (1 << (dp - 1)) + tp;
            int ha = hp >> (dp - a);
            float da = means[(hp - 1) * 64 + lane] - means[(ha - 1) * 64 + lane];
            float s = da * da;
            #pragma unroll
            for (int o = 32; o; o >>= 1) s += __shfl_xor(s, o, 64);
            if (lane == 0) {
                float v = __expf(-s * 0.015625f);
                int ta = ha - (1 << (a - 1));
                long long voff = 0;
                for (int jj = 1; jj <= a - 1; ++jj)
                    if ((ta >> (a - 1 - jj)) & 1) voff += cV[jj + 1];
                long long q = cN[dp] - 1;
                for (int jj = a; jj <= dp - 1; ++jj)
                    if ((tp >> (dp - 1 - jj)) & 1) q += cN[jj + 1];
                long long m = cN[a] - 1;
                long long co = voff + 2 * cV[a + 1];
                out[VALS_OFF + co + q]     = v;
                out[VALS_OFF + co + m + q] = v;
            }
        } else if (lane == 0) {
            int h = wv - 642 + 1;
            int d = 32 - __clz(h);
            int t = h - (1 << (d - 1));
            long long voff = 0;
            for (int jj = 1; jj <= d - 1; ++jj)
                if ((t >> (d - 1 - jj)) & 1) voff += cV[jj + 1];
            long long m = cN[d] - 1;
            out[VALS_OFF + voff + 2 * cV[d + 1] + 2 * m] = 1.0f;
        }
    }
}

extern "C" void kernel_launch(void* const* d_in, const int* in_sizes, int n_in,
                              void* d_out, int out_size, void* d_ws, size_t ws_size,
                              hipStream_t stream) {
    const float* X = (const float*)d_in[0];
    float* out = (float*)d_out;

    float* part  = (float*)d_ws;              // 1024*64
    float* xn    = part + 1024 * 64;          // 65536
    float* means = xn + 65536;                // 127*64
    float* mn2   = means + 127 * 64;          // 127

    if (out_size != (int)OUT_TOTAL) return;
    if (ws_size < (size_t)(1024 * 64 + 65536 + 127 * 64 + 128) * sizeof(float)) return;

    r16_sums <<<1024,   256, 0, stream>>>(X, part);
    r16_norm <<<16384,  256, 0, stream>>>(X, xn);
    r16_means<<<127,     64, 0, stream>>>(part, means, mn2, out);
    r16_leaf <<<2048,   256, 0, stream>>>(X, xn, out);
    r16_rest <<<RB_ALL, 256, 0, stream>>>(X, xn, means, mn2, out);
}

// Round 17
// 242.241 us; speedup vs baseline: 1.5857x; 1.5857x over previous
//
#include <hip/hip_runtime.h>
#include <hip/hip_bf16.h>
#include <stdint.h>

// ROUND 17 = verbatim revert to round-14 code (measured best: 244 us).
// r15 (318) and r16 (384) both regressed vs r14; both predictions failed, so
// this round re-measures the best-known config to bound run-to-run variance
// before further changes.
// d_out FLOAT32. Layout (f32 elems): nodes [0,4202432) | idx0 [4202432,38675779)
// | idx1 [38675779,73149126) | vals [73149126,107622473)
#define NNZ       34473347LL
#define IDX0_OFF  4202432LL
#define IDX1_OFF  38675779LL
#define VALS_OFF  73149126LL
#define OUT_TOTAL 107622473LL

__constant__ int       cN[9] = {0, 65663, 32831, 16415, 8207, 4103, 2051, 1025, 512};
__constant__ long long cV[9] = {0, 34473347LL, 17171011LL, 8552675LL, 4259923LL,
                                2121755LL, 1056775LL, 526337LL, 262144LL};
__constant__ int       cSZ[8] = {0, 131325, 65661, 32829, 16413, 8205, 4101, 2049};
__constant__ int gD[21] = {2, 3,3, 4,4,4, 5,5,5,5, 6,6,6,6,6, 7,7,7,7,7,7};
__constant__ int gA[21] = {1, 1,2, 1,2,3, 1,2,3,4, 1,2,3,4,5, 1,2,3,4,5,6};
__constant__ int gB[21] = {0, 2,6, 10,18,26, 34,50,66,82, 98,130,162,194,226,
                           258,322,386,450,514,578};

// ---- stage 1: per-leaf feature sums (ws) ----
__global__ void r17_sums(const float* __restrict__ X, float* __restrict__ sums) {
    __shared__ float part[4][64];
    int t = blockIdx.x;
    int k = threadIdx.x & 63, p = threadIdx.x >> 6;
    const float* xp = X + (long long)t * 32768;
    float s = 0.f;
    for (int i = p * 128; i < p * 128 + 128; ++i) s += xp[(long long)i * 64 + k];
    part[p][k] = s;
    __syncthreads();
    if (threadIdx.x < 64)
        sums[t * 64 + k] = part[0][k] + part[1][k] + part[2][k] + part[3][k];
}

// ---- stage 2: row norms (ws) ----
__global__ void r17_norm(const float* __restrict__ X, float* __restrict__ xn) {
    int w = threadIdx.x >> 6, lane = threadIdx.x & 63;
    long long row = (long long)blockIdx.x * 4 + w;
    float x = X[row * 64 + lane];
    float s = x * x;
    #pragma unroll
    for (int o = 32; o; o >>= 1) s += __shfl_xor(s, o, 64);
    if (lane == 0) xn[row] = s;
}

// ---- stage 3: ALL means in parallel (range-mean identity) ----
__global__ void r17_means(const float* __restrict__ sums, float* __restrict__ means,
                          float* __restrict__ mn2, float* __restrict__ out) {
    int h = blockIdx.x + 1;
    int k = threadIdx.x;
    int d = 32 - __clz(h);
    int t = h - (1 << (d - 1));
    int lo = t << (8 - d), cnt = 1 << (8 - d);
    float s = 0.f;
    for (int l = lo; l < lo + cnt; ++l) s += sums[l * 64 + k];
    float mv = s / (float)(1 << (17 - d));
    means[blockIdx.x * 64 + k] = mv;
    long long bb = 0;
    for (int jj = 1; jj <= d - 1; ++jj)
        if ((t >> (d - 1 - jj)) & 1) bb += cN[jj + 1];
    out[(bb + cN[d] - 1) * 64 + k] = mv;
    float sq = mv * mv;
    #pragma unroll
    for (int o = 32; o; o >>= 1) sq += __shfl_xor(sq, o, 64);
    if (k == 0) mn2[blockIdx.x] = sq;
}

// ---- stage 4: FUSED leaf tiles -> vals + idx0 + idx1 ----
__global__ __launch_bounds__(256) void r17_leaf(const float* __restrict__ X,
                                                const float* __restrict__ xn,
                                                float* __restrict__ out) {
    __shared__ float As[32][128];
    __shared__ float Bs[32][128];
    int bx = blockIdx.x;
    int t = bx >> 4, tile = bx & 15, br = tile >> 2, bc = tile & 3;
    int tid = threadIdx.x;

    long long voff = 0; int nb = 0;
    #pragma unroll
    for (int jj = 1; jj <= 7; ++jj)
        if ((t >> (7 - jj)) & 1) { voff += cV[jj + 1]; nb += cN[jj + 1]; }

    const float* xleaf = X + (long long)t * 32768;

    float acc[8][8] = {};
    for (int ks = 0; ks < 64; ks += 32) {
        __syncthreads();
        #pragma unroll
        for (int u = 0; u < 4; ++u) {
            int idx = tid * 4 + u;
            int i = idx >> 3, k4 = (idx & 7) * 4;
            float4 va = *(const float4*)&xleaf[(long long)(br * 128 + i) * 64 + ks + k4];
            As[k4 + 0][i] = va.x; As[k4 + 1][i] = va.y; As[k4 + 2][i] = va.z; As[k4 + 3][i] = va.w;
            float4 vb = *(const float4*)&xleaf[(long long)(bc * 128 + i) * 64 + ks + k4];
            Bs[k4 + 0][i] = vb.x; Bs[k4 + 1][i] = vb.y; Bs[k4 + 2][i] = vb.z; Bs[k4 + 3][i] = vb.w;
        }
        __syncthreads();
        int ty = tid >> 4, tx = tid & 15;
        for (int k = 0; k < 32; ++k) {
            float a[8], bb[8];
            *(float4*)&a[0]  = *(const float4*)&As[k][ty * 8];
            *(float4*)&a[4]  = *(const float4*)&As[k][ty * 8 + 4];
            *(float4*)&bb[0] = *(const float4*)&Bs[k][tx * 4];
            *(float4*)&bb[4] = *(const float4*)&Bs[k][64 + tx * 4];
            #pragma unroll
            for (int r = 0; r < 8; ++r)
                #pragma unroll
                for (int c = 0; c < 8; ++c) acc[r][c] += a[r] * bb[c];
        }
    }

    int ty = tid >> 4, tx = tid & 15;
    int r0g = br * 128 + ty * 8;
    int cga = bc * 128 + tx * 4;

    float nbv[8], i1v[8];
    #pragma unroll
    for (int c = 0; c < 4; ++c) {
        nbv[c]     = xn[(long long)t * 512 + cga + c];
        nbv[4 + c] = xn[(long long)t * 512 + cga + 64 + c];
        i1v[c]     = (float)(nb + cga + c);
        i1v[4 + c] = (float)(nb + cga + 64 + c);
    }

    #pragma unroll
    for (int r = 0; r < 8; ++r) {
        int grow = r0g + r;
        float nar = xn[(long long)t * 512 + grow];
        float i0f = (float)(nb + grow);
        long long rb = voff + (long long)grow * 512;
        #pragma unroll
        for (int h = 0; h < 2; ++h) {
            long long cb = rb + cga + h * 64;
            #pragma unroll
            for (int c = 0; c < 4; ++c) {
                float d2 = nar + nbv[h * 4 + c] - 2.0f * acc[r][h * 4 + c];
                out[VALS_OFF + cb + c] = __expf(-d2 * 0.015625f);
                out[IDX0_OFF + cb + c] = i0f;
                out[IDX1_OFF + cb + c] = i1v[h * 4 + c];
            }
        }
    }
}

// ---- stage 5: internal-chunk X-row values, row-centric ----
__global__ __launch_bounds__(256) void r17_int(const float* __restrict__ X,
                                               const float* __restrict__ xn,
                                               const float* __restrict__ means,
                                               const float* __restrict__ mn2,
                                               float* __restrict__ out) {
    int lane = threadIdx.x & 63;
    int wv = (blockIdx.x << 2) + (threadIdx.x >> 6);   // 16384 waves
    for (int it = 0; it < 4; ++it) {
        int r = wv + (it << 14);                       // 65536 rows
        float x = X[(long long)r * 64 + lane];
        float xnr = xn[r];
        int t7 = r >> 9, col = r & 511;
        float dot[7];
        #pragma unroll
        for (int d = 1; d <= 7; ++d) {
            int h0 = (1 << (d - 1)) + (r >> (17 - d)) - 1;
            float p = x * means[h0 * 64 + lane];
            #pragma unroll
            for (int o = 32; o; o >>= 1) p += __shfl_xor(p, o, 64);
            dot[d - 1] = p;
        }
        if (lane == 0) {
            long long voff = 0;
            #pragma unroll
            for (int d = 1; d <= 7; ++d) {
                int h0 = (1 << (d - 1)) + (r >> (17 - d)) - 1;
                long long q = col;
                #pragma unroll
                for (int jj = 1; jj <= 7; ++jj)
                    if (jj >= d && ((t7 >> (7 - jj)) & 1)) q += cN[jj + 1];
                long long m = cN[d] - 1;
                long long co = voff + 2 * cV[d + 1];
                float v = __expf(-(xnr - 2.0f * dot[d - 1] + mn2[h0]) * 0.015625f);
                out[VALS_OFF + co + q]     = v;
                out[VALS_OFF + co + m + q] = v;
                if ((t7 >> (7 - d)) & 1) voff += cV[d + 1];
            }
        }
    }
}

// ---- stage 6: mean-vs-mean pairs (642) + the 127 "1.0" entries ----
__global__ void r17_meanpairs(const float* __restrict__ means, float* __restrict__ out) {
    int wv = (blockIdx.x << 2) + (threadIdx.x >> 6);
    int lane = threadIdx.x & 63;
    if (wv >= 769) return;
    if (wv < 642) {
        int g = 0;
        while (g < 20 && wv >= gB[g + 1]) ++g;
        int dp = gD[g], a = gA[g];
        int tp = wv - gB[g];
        int hp = (1 << (dp - 1)) + tp;
        int ha = hp >> (dp - a);
        float da = means[(hp - 1) * 64 + lane] - means[(ha - 1) * 64 + lane];
        float s = da * da;
        #pragma unroll
        for (int o = 32; o; o >>= 1) s += __shfl_xor(s, o, 64);
        if (lane == 0) {
            float v = __expf(-s * 0.015625f);
            int ta = ha - (1 << (a - 1));
            long long voff = 0;
            for (int jj = 1; jj <= a - 1; ++jj)
                if ((ta >> (a - 1 - jj)) & 1) voff += cV[jj + 1];
            long long q = cN[dp] - 1;
            for (int jj = a; jj <= dp - 1; ++jj)
                if ((tp >> (dp - 1 - jj)) & 1) q += cN[jj + 1];
            long long m = cN[a] - 1;
            long long co = voff + 2 * cV[a + 1];
            out[VALS_OFF + co + q]     = v;
            out[VALS_OFF + co + m + q] = v;
        }
    } else if (lane == 0) {
        int h = wv - 642 + 1;
        int d = 32 - __clz(h);
        int t = h - (1 << (d - 1));
        long long voff = 0;
        for (int jj = 1; jj <= d - 1; ++jj)
            if ((t >> (d - 1 - jj)) & 1) voff += cV[jj + 1];
        long long m = cN[d] - 1;
        out[VALS_OFF + voff + 2 * cV[d + 1] + 2 * m] = 1.0f;
    }
}

// ---- stage 7: internal-chunk indices ----
__global__ void r17_idx_int(float* __restrict__ out) {
    int d = blockIdx.y + 1;
    int sz = cSZ[d];
    int m = cN[d] - 1;
    long long pos = (long long)blockIdx.x * 256 + threadIdx.x;
    long long tot = (long long)(1 << (d - 1)) * sz;
    if (pos >= tot) return;
    int t = (int)(pos / sz);
    int e = (int)(pos % sz);
    long long voff = 0; long long base = 0;
    for (int jj = 1; jj < d; ++jj)
        if ((t >> (d - 1 - jj)) & 1) { voff += cV[jj + 1]; base += cN[jj + 1]; }
    long long p = voff + 2 * cV[d + 1] + e;
    long long i0, i1;
    if (e < m)          { i0 = base + e;     i1 = base + m; }
    else if (e < 2 * m) { i0 = base + m;     i1 = base + e - m; }
    else                { i0 = base + m;     i1 = base + m; }
    out[IDX0_OFF + p] = (float)i0;
    out[IDX1_OFF + p] = (float)i1;
}

// ---- stage 8: leaf-node rows ----
__global__ void r17_nodeL(const float* __restrict__ X, float* __restrict__ out) {
    long long e = ((long long)blockIdx.x * 256 + threadIdx.x) * 4;
    int t = (int)(e >> 15);
    int l = (int)(e & 32767);
    int j = l >> 6, k = l & 63;
    int b = 0;
    #pragma unroll
    for (int jj = 1; jj <= 7; ++jj) if ((t >> (7 - jj)) & 1) b += cN[jj + 1];
    float4 v = *(const float4*)&X[e];
    *(float4*)&out[((long long)b + j) * 64 + k] = v;
}

extern "C" void kernel_launch(void* const* d_in, const int* in_sizes, int n_in,
                              void* d_out, int out_size, void* d_ws, size_t ws_size,
                              hipStream_t stream) {
    const float* X = (const float*)d_in[0];
    float* out = (float*)d_out;

    float* sums  = (float*)d_ws;              // 128*64
    float* xn    = sums + 128 * 64;           // 65536
    float* means = xn + 65536;                // 127*64
    float* mn2   = means + 127 * 64;          // 127

    if (out_size != (int)OUT_TOTAL) return;
    if (ws_size < (size_t)(128 * 64 + 65536 + 127 * 64 + 128) * sizeof(float)) return;

    r17_sums     <<<128,   256, 0, stream>>>(X, sums);
    r17_norm     <<<16384, 256, 0, stream>>>(X, xn);
    r17_means    <<<127,    64, 0, stream>>>(sums, means, mn2, out);
    r17_leaf     <<<2048,  256, 0, stream>>>(X, xn, out);
    r17_int      <<<4096,  256, 0, stream>>>(X, xn, means, mn2, out);
    r17_meanpairs<<<193,   256, 0, stream>>>(means, out);
    r17_idx_int  <<<dim3(514, 7), 256, 0, stream>>>(out);
    r17_nodeL    <<<4096,  256, 0, stream>>>(X, out);
}

// Round 18
// 239.159 us; speedup vs baseline: 1.6061x; 1.0129x over previous
//
#include <hip/hip_runtime.h>
#include <hip/hip_bf16.h>
#include <stdint.h>

// ROUND 18 = r17 (242 us baseline) + ONE change: leaf epilogue stores
// vectorized as 4B-aligned dwordx4 (ext_vector_type(4) aligned(4)) --
// region bases are odd so 16B alignment is impossible, but gfx950
// global_store_dwordx4 only requires dword alignment.
// d_out FLOAT32. Layout (f32 elems): nodes [0,4202432) | idx0 [4202432,38675779)
// | idx1 [38675779,73149126) | vals [73149126,107622473)
#define NNZ       34473347LL
#define IDX0_OFF  4202432LL
#define IDX1_OFF  38675779LL
#define VALS_OFF  73149126LL
#define OUT_TOTAL 107622473LL

typedef float f4a __attribute__((ext_vector_type(4), aligned(4)));

__constant__ int       cN[9] = {0, 65663, 32831, 16415, 8207, 4103, 2051, 1025, 512};
__constant__ long long cV[9] = {0, 34473347LL, 17171011LL, 8552675LL, 4259923LL,
                                2121755LL, 1056775LL, 526337LL, 262144LL};
__constant__ int       cSZ[8] = {0, 131325, 65661, 32829, 16413, 8205, 4101, 2049};
__constant__ int gD[21] = {2, 3,3, 4,4,4, 5,5,5,5, 6,6,6,6,6, 7,7,7,7,7,7};
__constant__ int gA[21] = {1, 1,2, 1,2,3, 1,2,3,4, 1,2,3,4,5, 1,2,3,4,5,6};
__constant__ int gB[21] = {0, 2,6, 10,18,26, 34,50,66,82, 98,130,162,194,226,
                           258,322,386,450,514,578};

// ---- stage 1: per-leaf feature sums (ws) ----
__global__ void r18_sums(const float* __restrict__ X, float* __restrict__ sums) {
    __shared__ float part[4][64];
    int t = blockIdx.x;
    int k = threadIdx.x & 63, p = threadIdx.x >> 6;
    const float* xp = X + (long long)t * 32768;
    float s = 0.f;
    for (int i = p * 128; i < p * 128 + 128; ++i) s += xp[(long long)i * 64 + k];
    part[p][k] = s;
    __syncthreads();
    if (threadIdx.x < 64)
        sums[t * 64 + k] = part[0][k] + part[1][k] + part[2][k] + part[3][k];
}

// ---- stage 2: row norms (ws) ----
__global__ void r18_norm(const float* __restrict__ X, float* __restrict__ xn) {
    int w = threadIdx.x >> 6, lane = threadIdx.x & 63;
    long long row = (long long)blockIdx.x * 4 + w;
    float x = X[row * 64 + lane];
    float s = x * x;
    #pragma unroll
    for (int o = 32; o; o >>= 1) s += __shfl_xor(s, o, 64);
    if (lane == 0) xn[row] = s;
}

// ---- stage 3: ALL means in parallel (range-mean identity) ----
__global__ void r18_means(const float* __restrict__ sums, float* __restrict__ means,
                          float* __restrict__ mn2, float* __restrict__ out) {
    int h = blockIdx.x + 1;
    int k = threadIdx.x;
    int d = 32 - __clz(h);
    int t = h - (1 << (d - 1));
    int lo = t << (8 - d), cnt = 1 << (8 - d);
    float s = 0.f;
    for (int l = lo; l < lo + cnt; ++l) s += sums[l * 64 + k];
    float mv = s / (float)(1 << (17 - d));
    means[blockIdx.x * 64 + k] = mv;
    long long bb = 0;
    for (int jj = 1; jj <= d - 1; ++jj)
        if ((t >> (d - 1 - jj)) & 1) bb += cN[jj + 1];
    out[(bb + cN[d] - 1) * 64 + k] = mv;
    float sq = mv * mv;
    #pragma unroll
    for (int o = 32; o; o >>= 1) sq += __shfl_xor(sq, o, 64);
    if (k == 0) mn2[blockIdx.x] = sq;
}

// ---- stage 4: FUSED leaf tiles -> vals + idx0 + idx1 (dwordx4 stores) ----
__global__ __launch_bounds__(256) void r18_leaf(const float* __restrict__ X,
                                                const float* __restrict__ xn,
                                                float* __restrict__ out) {
    __shared__ float As[32][128];
    __shared__ float Bs[32][128];
    int bx = blockIdx.x;
    int t = bx >> 4, tile = bx & 15, br = tile >> 2, bc = tile & 3;
    int tid = threadIdx.x;

    long long voff = 0; int nb = 0;
    #pragma unroll
    for (int jj = 1; jj <= 7; ++jj)
        if ((t >> (7 - jj)) & 1) { voff += cV[jj + 1]; nb += cN[jj + 1]; }

    const float* xleaf = X + (long long)t * 32768;

    float acc[8][8] = {};
    for (int ks = 0; ks < 64; ks += 32) {
        __syncthreads();
        #pragma unroll
        for (int u = 0; u < 4; ++u) {
            int idx = tid * 4 + u;
            int i = idx >> 3, k4 = (idx & 7) * 4;
            float4 va = *(const float4*)&xleaf[(long long)(br * 128 + i) * 64 + ks + k4];
            As[k4 + 0][i] = va.x; As[k4 + 1][i] = va.y; As[k4 + 2][i] = va.z; As[k4 + 3][i] = va.w;
            float4 vb = *(const float4*)&xleaf[(long long)(bc * 128 + i) * 64 + ks + k4];
            Bs[k4 + 0][i] = vb.x; Bs[k4 + 1][i] = vb.y; Bs[k4 + 2][i] = vb.z; Bs[k4 + 3][i] = vb.w;
        }
        __syncthreads();
        int ty = tid >> 4, tx = tid & 15;
        for (int k = 0; k < 32; ++k) {
            float a[8], bb[8];
            *(float4*)&a[0]  = *(const float4*)&As[k][ty * 8];
            *(float4*)&a[4]  = *(const float4*)&As[k][ty * 8 + 4];
            *(float4*)&bb[0] = *(const float4*)&Bs[k][tx * 4];
            *(float4*)&bb[4] = *(const float4*)&Bs[k][64 + tx * 4];
            #pragma unroll
            for (int r = 0; r < 8; ++r)
                #pragma unroll
                for (int c = 0; c < 8; ++c) acc[r][c] += a[r] * bb[c];
        }
    }

    int ty = tid >> 4, tx = tid & 15;
    int r0g = br * 128 + ty * 8;
    int cga = bc * 128 + tx * 4;

    float nbv[8];
    f4a i1q[2];
    #pragma unroll
    for (int c = 0; c < 4; ++c) {
        nbv[c]     = xn[(long long)t * 512 + cga + c];
        nbv[4 + c] = xn[(long long)t * 512 + cga + 64 + c];
        i1q[0][c]  = (float)(nb + cga + c);
        i1q[1][c]  = (float)(nb + cga + 64 + c);
    }

    #pragma unroll
    for (int r = 0; r < 8; ++r) {
        int grow = r0g + r;
        float nar = xn[(long long)t * 512 + grow];
        float i0f = (float)(nb + grow);
        f4a i0q = {i0f, i0f, i0f, i0f};
        long long rb = voff + (long long)grow * 512;
        #pragma unroll
        for (int h = 0; h < 2; ++h) {
            long long cb = rb + cga + h * 64;
            f4a vv;
            #pragma unroll
            for (int c = 0; c < 4; ++c) {
                float d2 = nar + nbv[h * 4 + c] - 2.0f * acc[r][h * 4 + c];
                vv[c] = __expf(-d2 * 0.015625f);
            }
            *(f4a*)&out[VALS_OFF + cb] = vv;
            *(f4a*)&out[IDX0_OFF + cb] = i0q;
            *(f4a*)&out[IDX1_OFF + cb] = i1q[h];
        }
    }
}

// ---- stage 5: internal-chunk X-row values, row-centric ----
__global__ __launch_bounds__(256) void r18_int(const float* __restrict__ X,
                                               const float* __restrict__ xn,
                                               const float* __restrict__ means,
                                               const float* __restrict__ mn2,
                                               float* __restrict__ out) {
    int lane = threadIdx.x & 63;
    int wv = (blockIdx.x << 2) + (threadIdx.x >> 6);   // 16384 waves
    for (int it = 0; it < 4; ++it) {
        int r = wv + (it << 14);                       // 65536 rows
        float x = X[(long long)r * 64 + lane];
        float xnr = xn[r];
        int t7 = r >> 9, col = r & 511;
        float dot[7];
        #pragma unroll
        for (int d = 1; d <= 7; ++d) {
            int h0 = (1 << (d - 1)) + (r >> (17 - d)) - 1;
            float p = x * means[h0 * 64 + lane];
            #pragma unroll
            for (int o = 32; o; o >>= 1) p += __shfl_xor(p, o, 64);
            dot[d - 1] = p;
        }
        if (lane == 0) {
            long long voff = 0;
            #pragma unroll
            for (int d = 1; d <= 7; ++d) {
                int h0 = (1 << (d - 1)) + (r >> (17 - d)) - 1;
                long long q = col;
                #pragma unroll
                for (int jj = 1; jj <= 7; ++jj)
                    if (jj >= d && ((t7 >> (7 - jj)) & 1)) q += cN[jj + 1];
                long long m = cN[d] - 1;
                long long co = voff + 2 * cV[d + 1];
                float v = __expf(-(xnr - 2.0f * dot[d - 1] + mn2[h0]) * 0.015625f);
                out[VALS_OFF + co + q]     = v;
                out[VALS_OFF + co + m + q] = v;
                if ((t7 >> (7 - d)) & 1) voff += cV[d + 1];
            }
        }
    }
}

// ---- stage 6: mean-vs-mean pairs (642) + the 127 "1.0" entries ----
__global__ void r18_meanpairs(const float* __restrict__ means, float* __restrict__ out) {
    int wv = (blockIdx.x << 2) + (threadIdx.x >> 6);
    int lane = threadIdx.x & 63;
    if (wv >= 769) return;
    if (wv < 642) {
        int g = 0;
        while (g < 20 && wv >= gB[g + 1]) ++g;
        int dp = gD[g], a = gA[g];
        int tp = wv - gB[g];
        int hp = (1 << (dp - 1)) + tp;
        int ha = hp >> (dp - a);
        float da = means[(hp - 1) * 64 + lane] - means[(ha - 1) * 64 + lane];
        float s = da * da;
        #pragma unroll
        for (int o = 32; o; o >>= 1) s += __shfl_xor(s, o, 64);
        if (lane == 0) {
            float v = __expf(-s * 0.015625f);
            int ta = ha - (1 << (a - 1));
            long long voff = 0;
            for (int jj = 1; jj <= a - 1; ++jj)
                if ((ta >> (a - 1 - jj)) & 1) voff += cV[jj + 1];
            long long q = cN[dp] - 1;
            for (int jj = a; jj <= dp - 1; ++jj)
                if ((tp >> (dp - 1 - jj)) & 1) q += cN[jj + 1];
            long long m = cN[a] - 1;
            long long co = voff + 2 * cV[a + 1];
            out[VALS_OFF + co + q]     = v;
            out[VALS_OFF + co + m + q] = v;
        }
    } else if (lane == 0) {
        int h = wv - 642 + 1;
        int d = 32 - __clz(h);
        int t = h - (1 << (d - 1));
        long long voff = 0;
        for (int jj = 1; jj <= d - 1; ++jj)
            if ((t >> (d - 1 - jj)) & 1) voff += cV[jj + 1];
        long long m = cN[d] - 1;
        out[VALS_OFF + voff + 2 * cV[d + 1] + 2 * m] = 1.0f;
    }
}

// ---- stage 7: internal-chunk indices ----
__global__ void r18_idx_int(float* __restrict__ out) {
    int d = blockIdx.y + 1;
    int sz = cSZ[d];
    int m = cN[d] - 1;
    long long pos = (long long)blockIdx.x * 256 + threadIdx.x;
    long long tot = (long long)(1 << (d - 1)) * sz;
    if (pos >= tot) return;
    int t = (int)(pos / sz);
    int e = (int)(pos % sz);
    long long voff = 0; long long base = 0;
    for (int jj = 1; jj < d; ++jj)
        if ((t >> (d - 1 - jj)) & 1) { voff += cV[jj + 1]; base += cN[jj + 1]; }
    long long p = voff + 2 * cV[d + 1] + e;
    long long i0, i1;
    if (e < m)          { i0 = base + e;     i1 = base + m; }
    else if (e < 2 * m) { i0 = base + m;     i1 = base + e - m; }
    else                { i0 = base + m;     i1 = base + m; }
    out[IDX0_OFF + p] = (float)i0;
    out[IDX1_OFF + p] = (float)i1;
}

// ---- stage 8: leaf-node rows ----
__global__ void r18_nodeL(const float* __restrict__ X, float* __restrict__ out) {
    long long e = ((long long)blockIdx.x * 256 + threadIdx.x) * 4;
    int t = (int)(e >> 15);
    int l = (int)(e & 32767);
    int j = l >> 6, k = l & 63;
    int b = 0;
    #pragma unroll
    for (int jj = 1; jj <= 7; ++jj) if ((t >> (7 - jj)) & 1) b += cN[jj + 1];
    float4 v = *(const float4*)&X[e];
    *(float4*)&out[((long long)b + j) * 64 + k] = v;
}

extern "C" void kernel_launch(void* const* d_in, const int* in_sizes, int n_in,
                              void* d_out, int out_size, void* d_ws, size_t ws_size,
                              hipStream_t stream) {
    const float* X = (const float*)d_in[0];
    float* out = (float*)d_out;

    float* sums  = (float*)d_ws;              // 128*64
    float* xn    = sums + 128 * 64;           // 65536
    float* means = xn + 65536;                // 127*64
    float* mn2   = means + 127 * 64;          // 127

    if (out_size != (int)OUT_TOTAL) return;
    if (ws_size < (size_t)(128 * 64 + 65536 + 127 * 64 + 128) * sizeof(float)) return;

    r18_sums     <<<128,   256, 0, stream>>>(X, sums);
    r18_norm     <<<16384, 256, 0, stream>>>(X, xn);
    r18_means    <<<127,    64, 0, stream>>>(sums, means, mn2, out);
    r18_leaf     <<<2048,  256, 0, stream>>>(X, xn, out);
    r18_int      <<<4096,  256, 0, stream>>>(X, xn, means, mn2, out);
    r18_meanpairs<<<193,   256, 0, stream>>>(means, out);
    r18_idx_int  <<<dim3(514, 7), 256, 0, stream>>>(out);
    r18_nodeL    <<<4096,  256, 0, stream>>>(X, out);
}

// Round 19
// 232.464 us; speedup vs baseline: 1.6523x; 1.0288x over previous
//
#include <hip/hip_runtime.h>
#include <hip/hip_bf16.h>
#include <stdint.h>

// ROUND 19 = r18 (239 us) + ONE change: fuse the four LDS-free tail kernels
// (int | idx_int | nodeL | meanpairs) into one role-dispatched launch.
// sums/norm/means/leaf are byte-identical to r18. Single-variable test of
// role-fusion (r15/r16 regressions are now attributed to co-varied serial
// means/pre restructures, not fusion itself).
#define NNZ       34473347LL
#define IDX0_OFF  4202432LL
#define IDX1_OFF  38675779LL
#define VALS_OFF  73149126LL
#define OUT_TOTAL 107622473LL

typedef float f4a __attribute__((ext_vector_type(4), aligned(4)));

__constant__ int       cN[9] = {0, 65663, 32831, 16415, 8207, 4103, 2051, 1025, 512};
__constant__ long long cV[9] = {0, 34473347LL, 17171011LL, 8552675LL, 4259923LL,
                                2121755LL, 1056775LL, 526337LL, 262144LL};
__constant__ int       cSZ[8] = {0, 131325, 65661, 32829, 16413, 8205, 4101, 2049};
__constant__ int gD[21] = {2, 3,3, 4,4,4, 5,5,5,5, 6,6,6,6,6, 7,7,7,7,7,7};
__constant__ int gA[21] = {1, 1,2, 1,2,3, 1,2,3,4, 1,2,3,4,5, 1,2,3,4,5,6};
__constant__ int gB[21] = {0, 2,6, 10,18,26, 34,50,66,82, 98,130,162,194,226,
                           258,322,386,450,514,578};

// rest-kernel role layout: int [0,4096) | idx_int [4096,7694) | nodeL
// [7694,11790) | mp [11790,11983)
#define RB_IDXI  4096
#define RB_NODEL 7694
#define RB_MP    11790
#define RB_ALL   11983

// ---- stage 1: per-leaf feature sums (ws) ----
__global__ void r19_sums(const float* __restrict__ X, float* __restrict__ sums) {
    __shared__ float part[4][64];
    int t = blockIdx.x;
    int k = threadIdx.x & 63, p = threadIdx.x >> 6;
    const float* xp = X + (long long)t * 32768;
    float s = 0.f;
    for (int i = p * 128; i < p * 128 + 128; ++i) s += xp[(long long)i * 64 + k];
    part[p][k] = s;
    __syncthreads();
    if (threadIdx.x < 64)
        sums[t * 64 + k] = part[0][k] + part[1][k] + part[2][k] + part[3][k];
}

// ---- stage 2: row norms (ws) ----
__global__ void r19_norm(const float* __restrict__ X, float* __restrict__ xn) {
    int w = threadIdx.x >> 6, lane = threadIdx.x & 63;
    long long row = (long long)blockIdx.x * 4 + w;
    float x = X[row * 64 + lane];
    float s = x * x;
    #pragma unroll
    for (int o = 32; o; o >>= 1) s += __shfl_xor(s, o, 64);
    if (lane == 0) xn[row] = s;
}

// ---- stage 3: ALL means in parallel (range-mean identity) ----
__global__ void r19_means(const float* __restrict__ sums, float* __restrict__ means,
                          float* __restrict__ mn2, float* __restrict__ out) {
    int h = blockIdx.x + 1;
    int k = threadIdx.x;
    int d = 32 - __clz(h);
    int t = h - (1 << (d - 1));
    int lo = t << (8 - d), cnt = 1 << (8 - d);
    float s = 0.f;
    for (int l = lo; l < lo + cnt; ++l) s += sums[l * 64 + k];
    float mv = s / (float)(1 << (17 - d));
    means[blockIdx.x * 64 + k] = mv;
    long long bb = 0;
    for (int jj = 1; jj <= d - 1; ++jj)
        if ((t >> (d - 1 - jj)) & 1) bb += cN[jj + 1];
    out[(bb + cN[d] - 1) * 64 + k] = mv;
    float sq = mv * mv;
    #pragma unroll
    for (int o = 32; o; o >>= 1) sq += __shfl_xor(sq, o, 64);
    if (k == 0) mn2[blockIdx.x] = sq;
}

// ---- stage 4: FUSED leaf tiles -> vals + idx0 + idx1 (dwordx4 stores) ----
__global__ __launch_bounds__(256) void r19_leaf(const float* __restrict__ X,
                                                const float* __restrict__ xn,
                                                float* __restrict__ out) {
    __shared__ float As[32][128];
    __shared__ float Bs[32][128];
    int bx = blockIdx.x;
    int t = bx >> 4, tile = bx & 15, br = tile >> 2, bc = tile & 3;
    int tid = threadIdx.x;

    long long voff = 0; int nb = 0;
    #pragma unroll
    for (int jj = 1; jj <= 7; ++jj)
        if ((t >> (7 - jj)) & 1) { voff += cV[jj + 1]; nb += cN[jj + 1]; }

    const float* xleaf = X + (long long)t * 32768;

    float acc[8][8] = {};
    for (int ks = 0; ks < 64; ks += 32) {
        __syncthreads();
        #pragma unroll
        for (int u = 0; u < 4; ++u) {
            int idx = tid * 4 + u;
            int i = idx >> 3, k4 = (idx & 7) * 4;
            float4 va = *(const float4*)&xleaf[(long long)(br * 128 + i) * 64 + ks + k4];
            As[k4 + 0][i] = va.x; As[k4 + 1][i] = va.y; As[k4 + 2][i] = va.z; As[k4 + 3][i] = va.w;
            float4 vb = *(const float4*)&xleaf[(long long)(bc * 128 + i) * 64 + ks + k4];
            Bs[k4 + 0][i] = vb.x; Bs[k4 + 1][i] = vb.y; Bs[k4 + 2][i] = vb.z; Bs[k4 + 3][i] = vb.w;
        }
        __syncthreads();
        int ty = tid >> 4, tx = tid & 15;
        for (int k = 0; k < 32; ++k) {
            float a[8], bb[8];
            *(float4*)&a[0]  = *(const float4*)&As[k][ty * 8];
            *(float4*)&a[4]  = *(const float4*)&As[k][ty * 8 + 4];
            *(float4*)&bb[0] = *(const float4*)&Bs[k][tx * 4];
            *(float4*)&bb[4] = *(const float4*)&Bs[k][64 + tx * 4];
            #pragma unroll
            for (int r = 0; r < 8; ++r)
                #pragma unroll
                for (int c = 0; c < 8; ++c) acc[r][c] += a[r] * bb[c];
        }
    }

    int ty = tid >> 4, tx = tid & 15;
    int r0g = br * 128 + ty * 8;
    int cga = bc * 128 + tx * 4;

    float nbv[8];
    f4a i1q[2];
    #pragma unroll
    for (int c = 0; c < 4; ++c) {
        nbv[c]     = xn[(long long)t * 512 + cga + c];
        nbv[4 + c] = xn[(long long)t * 512 + cga + 64 + c];
        i1q[0][c]  = (float)(nb + cga + c);
        i1q[1][c]  = (float)(nb + cga + 64 + c);
    }

    #pragma unroll
    for (int r = 0; r < 8; ++r) {
        int grow = r0g + r;
        float nar = xn[(long long)t * 512 + grow];
        float i0f = (float)(nb + grow);
        f4a i0q = {i0f, i0f, i0f, i0f};
        long long rb = voff + (long long)grow * 512;
        #pragma unroll
        for (int h = 0; h < 2; ++h) {
            long long cb = rb + cga + h * 64;
            f4a vv;
            #pragma unroll
            for (int c = 0; c < 4; ++c) {
                float d2 = nar + nbv[h * 4 + c] - 2.0f * acc[r][h * 4 + c];
                vv[c] = __expf(-d2 * 0.015625f);
            }
            *(f4a*)&out[VALS_OFF + cb] = vv;
            *(f4a*)&out[IDX0_OFF + cb] = i0q;
            *(f4a*)&out[IDX1_OFF + cb] = i1q[h];
        }
    }
}

// ---- stage 5: FUSED tail: int | idx_int | nodeL | meanpairs ----
__global__ __launch_bounds__(256) void r19_rest(const float* __restrict__ X,
                                                const float* __restrict__ xn,
                                                const float* __restrict__ means,
                                                const float* __restrict__ mn2,
                                                float* __restrict__ out) {
    int bid = blockIdx.x;
    int tid = threadIdx.x;

    if (bid < RB_IDXI) {
        // ---- internal-chunk X-row values, row-centric (verbatim r18_int) ----
        int lane = tid & 63;
        int wv = (bid << 2) + (tid >> 6);
        for (int it = 0; it < 4; ++it) {
            int r = wv + (it << 14);
            float x = X[(long long)r * 64 + lane];
            float xnr = xn[r];
            int t7 = r >> 9, col = r & 511;
            float dot[7];
            #pragma unroll
            for (int d = 1; d <= 7; ++d) {
                int h0 = (1 << (d - 1)) + (r >> (17 - d)) - 1;
                float p = x * means[h0 * 64 + lane];
                #pragma unroll
                for (int o = 32; o; o >>= 1) p += __shfl_xor(p, o, 64);
                dot[d - 1] = p;
            }
            if (lane == 0) {
                long long voff = 0;
                #pragma unroll
                for (int d = 1; d <= 7; ++d) {
                    int h0 = (1 << (d - 1)) + (r >> (17 - d)) - 1;
                    long long q = col;
                    #pragma unroll
                    for (int jj = 1; jj <= 7; ++jj)
                        if (jj >= d && ((t7 >> (7 - jj)) & 1)) q += cN[jj + 1];
                    long long m = cN[d] - 1;
                    long long co = voff + 2 * cV[d + 1];
                    float v = __expf(-(xnr - 2.0f * dot[d - 1] + mn2[h0]) * 0.015625f);
                    out[VALS_OFF + co + q]     = v;
                    out[VALS_OFF + co + m + q] = v;
                    if ((t7 >> (7 - d)) & 1) voff += cV[d + 1];
                }
            }
        }
    } else if (bid < RB_NODEL) {
        // ---- internal-chunk indices (verbatim r18_idx_int) ----
        int local = bid - RB_IDXI;
        int d = local / 514 + 1;
        int bx = local % 514;
        int sz = cSZ[d];
        int m = cN[d] - 1;
        long long pos = (long long)bx * 256 + tid;
        long long tot = (long long)(1 << (d - 1)) * sz;
        if (pos < tot) {
            int t = (int)(pos / sz);
            int e = (int)(pos % sz);
            long long voff = 0; long long base = 0;
            for (int jj = 1; jj < d; ++jj)
                if ((t >> (d - 1 - jj)) & 1) { voff += cV[jj + 1]; base += cN[jj + 1]; }
            long long p = voff + 2 * cV[d + 1] + e;
            long long i0, i1;
            if (e < m)          { i0 = base + e;     i1 = base + m; }
            else if (e < 2 * m) { i0 = base + m;     i1 = base + e - m; }
            else                { i0 = base + m;     i1 = base + m; }
            out[IDX0_OFF + p] = (float)i0;
            out[IDX1_OFF + p] = (float)i1;
        }
    } else if (bid < RB_MP) {
        // ---- leaf-node rows (verbatim r18_nodeL) ----
        int local = bid - RB_NODEL;
        long long e = ((long long)local * 256 + tid) * 4;
        int t = (int)(e >> 15);
        int l = (int)(e & 32767);
        int j = l >> 6, k = l & 63;
        int b = 0;
        #pragma unroll
        for (int jj = 1; jj <= 7; ++jj) if ((t >> (7 - jj)) & 1) b += cN[jj + 1];
        float4 v = *(const float4*)&X[e];
        *(float4*)&out[((long long)b + j) * 64 + k] = v;
    } else {
        // ---- mean-vs-mean pairs + 1.0 entries (verbatim r18_meanpairs) ----
        int local = bid - RB_MP;
        int wv = (local << 2) + (tid >> 6);
        int lane = tid & 63;
        if (wv >= 769) return;
        if (wv < 642) {
            int g = 0;
            while (g < 20 && wv >= gB[g + 1]) ++g;
            int dp = gD[g], a = gA[g];
            int tp = wv - gB[g];
            int hp = (1 << (dp - 1)) + tp;
            int ha = hp >> (dp - a);
            float da = means[(hp - 1) * 64 + lane] - means[(ha - 1) * 64 + lane];
            float s = da * da;
            #pragma unroll
            for (int o = 32; o; o >>= 1) s += __shfl_xor(s, o, 64);
            if (lane == 0) {
                float v = __expf(-s * 0.015625f);
                int ta = ha - (1 << (a - 1));
                long long voff = 0;
                for (int jj = 1; jj <= a - 1; ++jj)
                    if ((ta >> (a - 1 - jj)) & 1) voff += cV[jj + 1];
                long long q = cN[dp] - 1;
                for (int jj = a; jj <= dp - 1; ++jj)
                    if ((tp >> (dp - 1 - jj)) & 1) q += cN[jj + 1];
                long long m = cN[a] - 1;
                long long co = voff + 2 * cV[a + 1];
                out[VALS_OFF + co + q]     = v;
                out[VALS_OFF + co + m + q] = v;
            }
        } else if (lane == 0) {
            int h = wv - 642 + 1;
            int d = 32 - __clz(h);
            int t = h - (1 << (d - 1));
            long long voff = 0;
            for (int jj = 1; jj <= d - 1; ++jj)
                if ((t >> (d - 1 - jj)) & 1) voff += cV[jj + 1];
            long long m = cN[d] - 1;
            out[VALS_OFF + voff + 2 * cV[d + 1] + 2 * m] = 1.0f;
        }
    }
}

extern "C" void kernel_launch(void* const* d_in, const int* in_sizes, int n_in,
                              void* d_out, int out_size, void* d_ws, size_t ws_size,
                              hipStream_t stream) {
    const float* X = (const float*)d_in[0];
    float* out = (float*)d_out;

    float* sums  = (float*)d_ws;              // 128*64
    float* xn    = sums + 128 * 64;           // 65536
    float* means = xn + 65536;                // 127*64
    float* mn2   = means + 127 * 64;          // 127

    if (out_size != (int)OUT_TOTAL) return;
    if (ws_size < (size_t)(128 * 64 + 65536 + 127 * 64 + 128) * sizeof(float)) return;

    r19_sums <<<128,    256, 0, stream>>>(X, sums);
    r19_norm <<<16384,  256, 0, stream>>>(X, xn);
    r19_means<<<127,     64, 0, stream>>>(sums, means, mn2, out);
    r19_leaf <<<2048,   256, 0, stream>>>(X, xn, out);
    r19_rest <<<RB_ALL, 256, 0, stream>>>(X, xn, means, mn2, out);
}

// Round 20
// 209.712 us; speedup vs baseline: 1.8316x; 1.1085x over previous
//
#include <hip/hip_runtime.h>
#include <hip/hip_bf16.h>
#include <stdint.h>

// ROUND 20 = r19 (232 us) + ONE change: int role restructured thread-per-row
// (no shuffles, wave-uniform means broadcast, coalesced q-stores).
// d_out FLOAT32. nodes [0,4202432) | idx0 | idx1 | vals (offsets below).
#define NNZ       34473347LL
#define IDX0_OFF  4202432LL
#define IDX1_OFF  38675779LL
#define VALS_OFF  73149126LL
#define OUT_TOTAL 107622473LL

typedef float f4a __attribute__((ext_vector_type(4), aligned(4)));

__constant__ int       cN[9] = {0, 65663, 32831, 16415, 8207, 4103, 2051, 1025, 512};
__constant__ long long cV[9] = {0, 34473347LL, 17171011LL, 8552675LL, 4259923LL,
                                2121755LL, 1056775LL, 526337LL, 262144LL};
__constant__ int       cSZ[8] = {0, 131325, 65661, 32829, 16413, 8205, 4101, 2049};
__constant__ int gD[21] = {2, 3,3, 4,4,4, 5,5,5,5, 6,6,6,6,6, 7,7,7,7,7,7};
__constant__ int gA[21] = {1, 1,2, 1,2,3, 1,2,3,4, 1,2,3,4,5, 1,2,3,4,5,6};
__constant__ int gB[21] = {0, 2,6, 10,18,26, 34,50,66,82, 98,130,162,194,226,
                           258,322,386,450,514,578};

// rest-kernel role layout
#define RB_IDXI  256            // int: [0,256)  (thread-per-row)
#define RB_NODEL 3854           // idx_int: [256,3854)   (514*7)
#define RB_MP    7950           // nodeL: [3854,7950)    (4096)
#define RB_ALL   8143           // mp: [7950,8143)       (193)

// ---- stage 1: per-leaf feature sums (ws) ----
__global__ void r20_sums(const float* __restrict__ X, float* __restrict__ sums) {
    __shared__ float part[4][64];
    int t = blockIdx.x;
    int k = threadIdx.x & 63, p = threadIdx.x >> 6;
    const float* xp = X + (long long)t * 32768;
    float s = 0.f;
    for (int i = p * 128; i < p * 128 + 128; ++i) s += xp[(long long)i * 64 + k];
    part[p][k] = s;
    __syncthreads();
    if (threadIdx.x < 64)
        sums[t * 64 + k] = part[0][k] + part[1][k] + part[2][k] + part[3][k];
}

// ---- stage 2: row norms (ws) ----
__global__ void r20_norm(const float* __restrict__ X, float* __restrict__ xn) {
    int w = threadIdx.x >> 6, lane = threadIdx.x & 63;
    long long row = (long long)blockIdx.x * 4 + w;
    float x = X[row * 64 + lane];
    float s = x * x;
    #pragma unroll
    for (int o = 32; o; o >>= 1) s += __shfl_xor(s, o, 64);
    if (lane == 0) xn[row] = s;
}

// ---- stage 3: ALL means in parallel (range-mean identity) ----
__global__ void r20_means(const float* __restrict__ sums, float* __restrict__ means,
                          float* __restrict__ mn2, float* __restrict__ out) {
    int h = blockIdx.x + 1;
    int k = threadIdx.x;
    int d = 32 - __clz(h);
    int t = h - (1 << (d - 1));
    int lo = t << (8 - d), cnt = 1 << (8 - d);
    float s = 0.f;
    for (int l = lo; l < lo + cnt; ++l) s += sums[l * 64 + k];
    float mv = s / (float)(1 << (17 - d));
    means[blockIdx.x * 64 + k] = mv;
    long long bb = 0;
    for (int jj = 1; jj <= d - 1; ++jj)
        if ((t >> (d - 1 - jj)) & 1) bb += cN[jj + 1];
    out[(bb + cN[d] - 1) * 64 + k] = mv;
    float sq = mv * mv;
    #pragma unroll
    for (int o = 32; o; o >>= 1) sq += __shfl_xor(sq, o, 64);
    if (k == 0) mn2[blockIdx.x] = sq;
}

// ---- stage 4: FUSED leaf tiles -> vals + idx0 + idx1 (dwordx4 stores) ----
__global__ __launch_bounds__(256) void r20_leaf(const float* __restrict__ X,
                                                const float* __restrict__ xn,
                                                float* __restrict__ out) {
    __shared__ float As[32][128];
    __shared__ float Bs[32][128];
    int bx = blockIdx.x;
    int t = bx >> 4, tile = bx & 15, br = tile >> 2, bc = tile & 3;
    int tid = threadIdx.x;

    long long voff = 0; int nb = 0;
    #pragma unroll
    for (int jj = 1; jj <= 7; ++jj)
        if ((t >> (7 - jj)) & 1) { voff += cV[jj + 1]; nb += cN[jj + 1]; }

    const float* xleaf = X + (long long)t * 32768;

    float acc[8][8] = {};
    for (int ks = 0; ks < 64; ks += 32) {
        __syncthreads();
        #pragma unroll
        for (int u = 0; u < 4; ++u) {
            int idx = tid * 4 + u;
            int i = idx >> 3, k4 = (idx & 7) * 4;
            float4 va = *(const float4*)&xleaf[(long long)(br * 128 + i) * 64 + ks + k4];
            As[k4 + 0][i] = va.x; As[k4 + 1][i] = va.y; As[k4 + 2][i] = va.z; As[k4 + 3][i] = va.w;
            float4 vb = *(const float4*)&xleaf[(long long)(bc * 128 + i) * 64 + ks + k4];
            Bs[k4 + 0][i] = vb.x; Bs[k4 + 1][i] = vb.y; Bs[k4 + 2][i] = vb.z; Bs[k4 + 3][i] = vb.w;
        }
        __syncthreads();
        int ty = tid >> 4, tx = tid & 15;
        for (int k = 0; k < 32; ++k) {
            float a[8], bb[8];
            *(float4*)&a[0]  = *(const float4*)&As[k][ty * 8];
            *(float4*)&a[4]  = *(const float4*)&As[k][ty * 8 + 4];
            *(float4*)&bb[0] = *(const float4*)&Bs[k][tx * 4];
            *(float4*)&bb[4] = *(const float4*)&Bs[k][64 + tx * 4];
            #pragma unroll
            for (int r = 0; r < 8; ++r)
                #pragma unroll
                for (int c = 0; c < 8; ++c) acc[r][c] += a[r] * bb[c];
        }
    }

    int ty = tid >> 4, tx = tid & 15;
    int r0g = br * 128 + ty * 8;
    int cga = bc * 128 + tx * 4;

    float nbv[8];
    f4a i1q[2];
    #pragma unroll
    for (int c = 0; c < 4; ++c) {
        nbv[c]     = xn[(long long)t * 512 + cga + c];
        nbv[4 + c] = xn[(long long)t * 512 + cga + 64 + c];
        i1q[0][c]  = (float)(nb + cga + c);
        i1q[1][c]  = (float)(nb + cga + 64 + c);
    }

    #pragma unroll
    for (int r = 0; r < 8; ++r) {
        int grow = r0g + r;
        float nar = xn[(long long)t * 512 + grow];
        float i0f = (float)(nb + grow);
        f4a i0q = {i0f, i0f, i0f, i0f};
        long long rb = voff + (long long)grow * 512;
        #pragma unroll
        for (int h = 0; h < 2; ++h) {
            long long cb = rb + cga + h * 64;
            f4a vv;
            #pragma unroll
            for (int c = 0; c < 4; ++c) {
                float d2 = nar + nbv[h * 4 + c] - 2.0f * acc[r][h * 4 + c];
                vv[c] = __expf(-d2 * 0.015625f);
            }
            *(f4a*)&out[VALS_OFF + cb] = vv;
            *(f4a*)&out[IDX0_OFF + cb] = i0q;
            *(f4a*)&out[IDX1_OFF + cb] = i1q[h];
        }
    }
}

// ---- stage 5: FUSED tail: int(thread-per-row) | idx_int | nodeL | meanpairs ----
__global__ __launch_bounds__(256) void r20_rest(const float* __restrict__ X,
                                                const float* __restrict__ xn,
                                                const float* __restrict__ means,
                                                const float* __restrict__ mn2,
                                                float* __restrict__ out) {
    int bid = blockIdx.x;
    int tid = threadIdx.x;

    if (bid < RB_IDXI) {
        // ---- internal-chunk X-row values: one THREAD per row ----
        int r = (bid << 8) + tid;                 // 0..65535; block within one leaf
        float4 xv[16];
        const float4* xp = (const float4*)(X + (long long)r * 64);
        #pragma unroll
        for (int i = 0; i < 16; ++i) xv[i] = xp[i];
        float xnr = xn[r];
        int t7 = r >> 9, col = r & 511;
        long long voff = 0;
        #pragma unroll
        for (int d = 1; d <= 7; ++d) {
            int h0 = (1 << (d - 1)) + (r >> (17 - d)) - 1;   // wave-uniform
            const float* mrow = means + h0 * 64;
            float dot = 0.f;
            #pragma unroll
            for (int i = 0; i < 16; ++i)
                dot += xv[i].x * mrow[4 * i] + xv[i].y * mrow[4 * i + 1]
                     + xv[i].z * mrow[4 * i + 2] + xv[i].w * mrow[4 * i + 3];
            long long q = col;
            #pragma unroll
            for (int jj = 1; jj <= 7; ++jj)
                if (jj >= d && ((t7 >> (7 - jj)) & 1)) q += cN[jj + 1];
            long long m = cN[d] - 1;
            long long co = voff + 2 * cV[d + 1];
            float v = __expf(-(xnr - 2.0f * dot + mn2[h0]) * 0.015625f);
            out[VALS_OFF + co + q]     = v;    // consecutive threads -> consecutive q
            out[VALS_OFF + co + m + q] = v;
            if ((t7 >> (7 - d)) & 1) voff += cV[d + 1];
        }
    } else if (bid < RB_NODEL) {
        // ---- internal-chunk indices ----
        int local = bid - RB_IDXI;
        int d = local / 514 + 1;
        int bx = local % 514;
        int sz = cSZ[d];
        int m = cN[d] - 1;
        long long pos = (long long)bx * 256 + tid;
        long long tot = (long long)(1 << (d - 1)) * sz;
        if (pos < tot) {
            int t = (int)(pos / sz);
            int e = (int)(pos % sz);
            long long voff = 0; long long base = 0;
            for (int jj = 1; jj < d; ++jj)
                if ((t >> (d - 1 - jj)) & 1) { voff += cV[jj + 1]; base += cN[jj + 1]; }
            long long p = voff + 2 * cV[d + 1] + e;
            long long i0, i1;
            if (e < m)          { i0 = base + e;     i1 = base + m; }
            else if (e < 2 * m) { i0 = base + m;     i1 = base + e - m; }
            else                { i0 = base + m;     i1 = base + m; }
            out[IDX0_OFF + p] = (float)i0;
            out[IDX1_OFF + p] = (float)i1;
        }
    } else if (bid < RB_MP) {
        // ---- leaf-node rows ----
        int local = bid - RB_NODEL;
        long long e = ((long long)local * 256 + tid) * 4;
        int t = (int)(e >> 15);
        int l = (int)(e & 32767);
        int j = l >> 6, k = l & 63;
        int b = 0;
        #pragma unroll
        for (int jj = 1; jj <= 7; ++jj) if ((t >> (7 - jj)) & 1) b += cN[jj + 1];
        float4 v = *(const float4*)&X[e];
        *(float4*)&out[((long long)b + j) * 64 + k] = v;
    } else {
        // ---- mean-vs-mean pairs + 1.0 entries ----
        int local = bid - RB_MP;
        int wv = (local << 2) + (tid >> 6);
        int lane = tid & 63;
        if (wv >= 769) return;
        if (wv < 642) {
            int g = 0;
            while (g < 20 && wv >= gB[g + 1]) ++g;
            int dp = gD[g], a = gA[g];
            int tp = wv - gB[g];
            int hp = (1 << (dp - 1)) + tp;
            int ha = hp >> (dp - a);
            float da = means[(hp - 1) * 64 + lane] - means[(ha - 1) * 64 + lane];
            float s = da * da;
            #pragma unroll
            for (int o = 32; o; o >>= 1) s += __shfl_xor(s, o, 64);
            if (lane == 0) {
                float v = __expf(-s * 0.015625f);
                int ta = ha - (1 << (a - 1));
                long long voff = 0;
                for (int jj = 1; jj <= a - 1; ++jj)
                    if ((ta >> (a - 1 - jj)) & 1) voff += cV[jj + 1];
                long long q = cN[dp] - 1;
                for (int jj = a; jj <= dp - 1; ++jj)
                    if ((tp >> (dp - 1 - jj)) & 1) q += cN[jj + 1];
                long long m = cN[a] - 1;
                long long co = voff + 2 * cV[a + 1];
                out[VALS_OFF + co + q]     = v;
                out[VALS_OFF + co + m + q] = v;
            }
        } else if (lane == 0) {
            int h = wv - 642 + 1;
            int d = 32 - __clz(h);
            int t = h - (1 << (d - 1));
            long long voff = 0;
            for (int jj = 1; jj <= d - 1; ++jj)
                if ((t >> (d - 1 - jj)) & 1) voff += cV[jj + 1];
            long long m = cN[d] - 1;
            out[VALS_OFF + voff + 2 * cV[d + 1] + 2 * m] = 1.0f;
        }
    }
}

extern "C" void kernel_launch(void* const* d_in, const int* in_sizes, int n_in,
                              void* d_out, int out_size, void* d_ws, size_t ws_size,
                              hipStream_t stream) {
    const float* X = (const float*)d_in[0];
    float* out = (float*)d_out;

    float* sums  = (float*)d_ws;              // 128*64
    float* xn    = sums + 128 * 64;           // 65536
    float* means = xn + 65536;                // 127*64
    float* mn2   = means + 127 * 64;          // 127

    if (out_size != (int)OUT_TOTAL) return;
    if (ws_size < (size_t)(128 * 64 + 65536 + 127 * 64 + 128) * sizeof(float)) return;

    r20_sums <<<128,    256, 0, stream>>>(X, sums);
    r20_norm <<<16384,  256, 0, stream>>>(X, xn);
    r20_means<<<127,     64, 0, stream>>>(sums, means, mn2, out);
    r20_leaf <<<2048,   256, 0, stream>>>(X, xn, out);
    r20_rest <<<RB_ALL, 256, 0, stream>>>(X, xn, means, mn2, out);
}

// Round 21
// 197.876 us; speedup vs baseline: 1.9412x; 1.0598x over previous
//
#include <hip/hip_runtime.h>
#include <hip/hip_bf16.h>
#include <stdint.h>

// ROUND 21 = r20 (209.7 us) + ONE change: leaf and rest fused into one
// role-dispatched launch (internals byte-identical). Tests whether rest's
// ~180 MB of independent store work hides under leaf's compute phases.
#define NNZ       34473347LL
#define IDX0_OFF  4202432LL
#define IDX1_OFF  38675779LL
#define VALS_OFF  73149126LL
#define OUT_TOTAL 107622473LL

typedef float f4a __attribute__((ext_vector_type(4), aligned(4)));

__constant__ int       cN[9] = {0, 65663, 32831, 16415, 8207, 4103, 2051, 1025, 512};
__constant__ long long cV[9] = {0, 34473347LL, 17171011LL, 8552675LL, 4259923LL,
                                2121755LL, 1056775LL, 526337LL, 262144LL};
__constant__ int       cSZ[8] = {0, 131325, 65661, 32829, 16413, 8205, 4101, 2049};
__constant__ int gD[21] = {2, 3,3, 4,4,4, 5,5,5,5, 6,6,6,6,6, 7,7,7,7,7,7};
__constant__ int gA[21] = {1, 1,2, 1,2,3, 1,2,3,4, 1,2,3,4,5, 1,2,3,4,5,6};
__constant__ int gB[21] = {0, 2,6, 10,18,26, 34,50,66,82, 98,130,162,194,226,
                           258,322,386,450,514,578};

// main-kernel role layout: leaf [0,2048) | int [2048,2304) | idx_int
// [2304,5902) | nodeL [5902,9998) | mp [9998,10191)
#define MB_LEAF  2048
#define MB_INT   2304
#define MB_IDXI  5902
#define MB_NODEL 9998
#define MB_ALL   10191

// ---- stage 1: per-leaf feature sums (ws) ----
__global__ void r21_sums(const float* __restrict__ X, float* __restrict__ sums) {
    __shared__ float part[4][64];
    int t = blockIdx.x;
    int k = threadIdx.x & 63, p = threadIdx.x >> 6;
    const float* xp = X + (long long)t * 32768;
    float s = 0.f;
    for (int i = p * 128; i < p * 128 + 128; ++i) s += xp[(long long)i * 64 + k];
    part[p][k] = s;
    __syncthreads();
    if (threadIdx.x < 64)
        sums[t * 64 + k] = part[0][k] + part[1][k] + part[2][k] + part[3][k];
}

// ---- stage 2: row norms (ws) ----
__global__ void r21_norm(const float* __restrict__ X, float* __restrict__ xn) {
    int w = threadIdx.x >> 6, lane = threadIdx.x & 63;
    long long row = (long long)blockIdx.x * 4 + w;
    float x = X[row * 64 + lane];
    float s = x * x;
    #pragma unroll
    for (int o = 32; o; o >>= 1) s += __shfl_xor(s, o, 64);
    if (lane == 0) xn[row] = s;
}

// ---- stage 3: ALL means in parallel (range-mean identity) ----
__global__ void r21_means(const float* __restrict__ sums, float* __restrict__ means,
                          float* __restrict__ mn2, float* __restrict__ out) {
    int h = blockIdx.x + 1;
    int k = threadIdx.x;
    int d = 32 - __clz(h);
    int t = h - (1 << (d - 1));
    int lo = t << (8 - d), cnt = 1 << (8 - d);
    float s = 0.f;
    for (int l = lo; l < lo + cnt; ++l) s += sums[l * 64 + k];
    float mv = s / (float)(1 << (17 - d));
    means[blockIdx.x * 64 + k] = mv;
    long long bb = 0;
    for (int jj = 1; jj <= d - 1; ++jj)
        if ((t >> (d - 1 - jj)) & 1) bb += cN[jj + 1];
    out[(bb + cN[d] - 1) * 64 + k] = mv;
    float sq = mv * mv;
    #pragma unroll
    for (int o = 32; o; o >>= 1) sq += __shfl_xor(sq, o, 64);
    if (k == 0) mn2[blockIdx.x] = sq;
}

// ---- stage 4: MAIN fused kernel: leaf | int | idx_int | nodeL | meanpairs ----
__global__ __launch_bounds__(256) void r21_main(const float* __restrict__ X,
                                                const float* __restrict__ xn,
                                                const float* __restrict__ means,
                                                const float* __restrict__ mn2,
                                                float* __restrict__ out) {
    __shared__ float As[32][128];
    __shared__ float Bs[32][128];
    int bid = blockIdx.x;
    int tid = threadIdx.x;

    if (bid < MB_LEAF) {
        // ---------------- leaf tiles: vals + idx0 + idx1 ----------------
        int t = bid >> 4, tile = bid & 15, br = tile >> 2, bc = tile & 3;
        long long voff = 0; int nb = 0;
        #pragma unroll
        for (int jj = 1; jj <= 7; ++jj)
            if ((t >> (7 - jj)) & 1) { voff += cV[jj + 1]; nb += cN[jj + 1]; }
        const float* xleaf = X + (long long)t * 32768;

        float acc[8][8] = {};
        for (int ks = 0; ks < 64; ks += 32) {
            __syncthreads();
            #pragma unroll
            for (int u = 0; u < 4; ++u) {
                int idx = tid * 4 + u;
                int i = idx >> 3, k4 = (idx & 7) * 4;
                float4 va = *(const float4*)&xleaf[(long long)(br * 128 + i) * 64 + ks + k4];
                As[k4 + 0][i] = va.x; As[k4 + 1][i] = va.y; As[k4 + 2][i] = va.z; As[k4 + 3][i] = va.w;
                float4 vb = *(const float4*)&xleaf[(long long)(bc * 128 + i) * 64 + ks + k4];
                Bs[k4 + 0][i] = vb.x; Bs[k4 + 1][i] = vb.y; Bs[k4 + 2][i] = vb.z; Bs[k4 + 3][i] = vb.w;
            }
            __syncthreads();
            int ty = tid >> 4, tx = tid & 15;
            for (int k = 0; k < 32; ++k) {
                float a[8], bb[8];
                *(float4*)&a[0]  = *(const float4*)&As[k][ty * 8];
                *(float4*)&a[4]  = *(const float4*)&As[k][ty * 8 + 4];
                *(float4*)&bb[0] = *(const float4*)&Bs[k][tx * 4];
                *(float4*)&bb[4] = *(const float4*)&Bs[k][64 + tx * 4];
                #pragma unroll
                for (int r = 0; r < 8; ++r)
                    #pragma unroll
                    for (int c = 0; c < 8; ++c) acc[r][c] += a[r] * bb[c];
            }
        }

        int ty = tid >> 4, tx = tid & 15;
        int r0g = br * 128 + ty * 8;
        int cga = bc * 128 + tx * 4;

        float nbv[8];
        f4a i1q[2];
        #pragma unroll
        for (int c = 0; c < 4; ++c) {
            nbv[c]     = xn[(long long)t * 512 + cga + c];
            nbv[4 + c] = xn[(long long)t * 512 + cga + 64 + c];
            i1q[0][c]  = (float)(nb + cga + c);
            i1q[1][c]  = (float)(nb + cga + 64 + c);
        }

        #pragma unroll
        for (int r = 0; r < 8; ++r) {
            int grow = r0g + r;
            float nar = xn[(long long)t * 512 + grow];
            float i0f = (float)(nb + grow);
            f4a i0q = {i0f, i0f, i0f, i0f};
            long long rb = voff + (long long)grow * 512;
            #pragma unroll
            for (int h = 0; h < 2; ++h) {
                long long cb = rb + cga + h * 64;
                f4a vv;
                #pragma unroll
                for (int c = 0; c < 4; ++c) {
                    float d2 = nar + nbv[h * 4 + c] - 2.0f * acc[r][h * 4 + c];
                    vv[c] = __expf(-d2 * 0.015625f);
                }
                *(f4a*)&out[VALS_OFF + cb] = vv;
                *(f4a*)&out[IDX0_OFF + cb] = i0q;
                *(f4a*)&out[IDX1_OFF + cb] = i1q[h];
            }
        }
    } else if (bid < MB_INT) {
        // ---- internal-chunk X-row values: one THREAD per row ----
        int r = ((bid - MB_LEAF) << 8) + tid;
        float4 xv[16];
        const float4* xp = (const float4*)(X + (long long)r * 64);
        #pragma unroll
        for (int i = 0; i < 16; ++i) xv[i] = xp[i];
        float xnr = xn[r];
        int t7 = r >> 9, col = r & 511;
        long long voff = 0;
        #pragma unroll
        for (int d = 1; d <= 7; ++d) {
            int h0 = (1 << (d - 1)) + (r >> (17 - d)) - 1;   // wave-uniform
            const float* mrow = means + h0 * 64;
            float dot = 0.f;
            #pragma unroll
            for (int i = 0; i < 16; ++i)
                dot += xv[i].x * mrow[4 * i] + xv[i].y * mrow[4 * i + 1]
                     + xv[i].z * mrow[4 * i + 2] + xv[i].w * mrow[4 * i + 3];
            long long q = col;
            #pragma unroll
            for (int jj = 1; jj <= 7; ++jj)
                if (jj >= d && ((t7 >> (7 - jj)) & 1)) q += cN[jj + 1];
            long long m = cN[d] - 1;
            long long co = voff + 2 * cV[d + 1];
            float v = __expf(-(xnr - 2.0f * dot + mn2[h0]) * 0.015625f);
            out[VALS_OFF + co + q]     = v;
            out[VALS_OFF + co + m + q] = v;
            if ((t7 >> (7 - d)) & 1) voff += cV[d + 1];
        }
    } else if (bid < MB_IDXI) {
        // ---- internal-chunk indices ----
        int local = bid - MB_INT;
        int d = local / 514 + 1;
        int bx = local % 514;
        int sz = cSZ[d];
        int m = cN[d] - 1;
        long long pos = (long long)bx * 256 + tid;
        long long tot = (long long)(1 << (d - 1)) * sz;
        if (pos < tot) {
            int t = (int)(pos / sz);
            int e = (int)(pos % sz);
            long long voff = 0; long long base = 0;
            for (int jj = 1; jj < d; ++jj)
                if ((t >> (d - 1 - jj)) & 1) { voff += cV[jj + 1]; base += cN[jj + 1]; }
            long long p = voff + 2 * cV[d + 1] + e;
            long long i0, i1;
            if (e < m)          { i0 = base + e;     i1 = base + m; }
            else if (e < 2 * m) { i0 = base + m;     i1 = base + e - m; }
            else                { i0 = base + m;     i1 = base + m; }
            out[IDX0_OFF + p] = (float)i0;
            out[IDX1_OFF + p] = (float)i1;
        }
    } else if (bid < MB_NODEL) {
        // ---- leaf-node rows ----
        int local = bid - MB_IDXI;
        long long e = ((long long)local * 256 + tid) * 4;
        int t = (int)(e >> 15);
        int l = (int)(e & 32767);
        int j = l >> 6, k = l & 63;
        int b = 0;
        #pragma unroll
        for (int jj = 1; jj <= 7; ++jj) if ((t >> (7 - jj)) & 1) b += cN[jj + 1];
        float4 v = *(const float4*)&X[e];
        *(float4*)&out[((long long)b + j) * 64 + k] = v;
    } else {
        // ---- mean-vs-mean pairs + 1.0 entries ----
        int local = bid - MB_NODEL;
        int wv = (local << 2) + (tid >> 6);
        int lane = tid & 63;
        if (wv >= 769) return;
        if (wv < 642) {
            int g = 0;
            while (g < 20 && wv >= gB[g + 1]) ++g;
            int dp = gD[g], a = gA[g];
            int tp = wv - gB[g];
            int hp = (1 << (dp - 1)) + tp;
            int ha = hp >> (dp - a);
            float da = means[(hp - 1) * 64 + lane] - means[(ha - 1) * 64 + lane];
            float s = da * da;
            #pragma unroll
            for (int o = 32; o; o >>= 1) s += __shfl_xor(s, o, 64);
            if (lane == 0) {
                float v = __expf(-s * 0.015625f);
                int ta = ha - (1 << (a - 1));
                long long voff = 0;
                for (int jj = 1; jj <= a - 1; ++jj)
                    if ((ta >> (a - 1 - jj)) & 1) voff += cV[jj + 1];
                long long q = cN[dp] - 1;
                for (int jj = a; jj <= dp - 1; ++jj)
                    if ((tp >> (dp - 1 - jj)) & 1) q += cN[jj + 1];
                long long m = cN[a] - 1;
                long long co = voff + 2 * cV[a + 1];
                out[VALS_OFF + co + q]     = v;
                out[VALS_OFF + co + m + q] = v;
            }
        } else if (lane == 0) {
            int h = wv - 642 + 1;
            int d = 32 - __clz(h);
            int t = h - (1 << (d - 1));
            long long voff = 0;
            for (int jj = 1; jj <= d - 1; ++jj)
                if ((t >> (d - 1 - jj)) & 1) voff += cV[jj + 1];
            long long m = cN[d] - 1;
            out[VALS_OFF + voff + 2 * cV[d + 1] + 2 * m] = 1.0f;
        }
    }
}

extern "C" void kernel_launch(void* const* d_in, const int* in_sizes, int n_in,
                              void* d_out, int out_size, void* d_ws, size_t ws_size,
                              hipStream_t stream) {
    const float* X = (const float*)d_in[0];
    float* out = (float*)d_out;

    float* sums  = (float*)d_ws;              // 128*64
    float* xn    = sums + 128 * 64;           // 65536
    float* means = xn + 65536;                // 127*64
    float* mn2   = means + 127 * 64;          // 127

    if (out_size != (int)OUT_TOTAL) return;
    if (ws_size < (size_t)(128 * 64 + 65536 + 127 * 64 + 128) * sizeof(float)) return;

    r21_sums <<<128,    256, 0, stream>>>(X, sums);
    r21_norm <<<16384,  256, 0, stream>>>(X, xn);
    r21_means<<<127,     64, 0, stream>>>(sums, means, mn2, out);
    r21_main <<<MB_ALL, 256, 0, stream>>>(X, xn, means, mn2, out);
}

// Round 22
// 188.465 us; speedup vs baseline: 2.0381x; 1.0499x over previous
//
#include <hip/hip_runtime.h>
#include <hip/hip_bf16.h>
#include <stdint.h>

// ROUND 22 = r21 (197.9 us) + ONE change: norm kernel DELETED. Leaf computes
// row/col norms in-register alongside the GEMM (na[r]+=a^2, nb2[c]+=b^2);
// int role computes its row norm from xv registers. xn removed from ws.
#define NNZ       34473347LL
#define IDX0_OFF  4202432LL
#define IDX1_OFF  38675779LL
#define VALS_OFF  73149126LL
#define OUT_TOTAL 107622473LL

typedef float f4a __attribute__((ext_vector_type(4), aligned(4)));

__constant__ int       cN[9] = {0, 65663, 32831, 16415, 8207, 4103, 2051, 1025, 512};
__constant__ long long cV[9] = {0, 34473347LL, 17171011LL, 8552675LL, 4259923LL,
                                2121755LL, 1056775LL, 526337LL, 262144LL};
__constant__ int       cSZ[8] = {0, 131325, 65661, 32829, 16413, 8205, 4101, 2049};
__constant__ int gD[21] = {2, 3,3, 4,4,4, 5,5,5,5, 6,6,6,6,6, 7,7,7,7,7,7};
__constant__ int gA[21] = {1, 1,2, 1,2,3, 1,2,3,4, 1,2,3,4,5, 1,2,3,4,5,6};
__constant__ int gB[21] = {0, 2,6, 10,18,26, 34,50,66,82, 98,130,162,194,226,
                           258,322,386,450,514,578};

// main-kernel role layout: leaf [0,2048) | int [2048,2304) | idx_int
// [2304,5902) | nodeL [5902,9998) | mp [9998,10191)
#define MB_LEAF  2048
#define MB_INT   2304
#define MB_IDXI  5902
#define MB_NODEL 9998
#define MB_ALL   10191

// ---- stage 1: per-leaf feature sums (ws) ----
__global__ void r22_sums(const float* __restrict__ X, float* __restrict__ sums) {
    __shared__ float part[4][64];
    int t = blockIdx.x;
    int k = threadIdx.x & 63, p = threadIdx.x >> 6;
    const float* xp = X + (long long)t * 32768;
    float s = 0.f;
    for (int i = p * 128; i < p * 128 + 128; ++i) s += xp[(long long)i * 64 + k];
    part[p][k] = s;
    __syncthreads();
    if (threadIdx.x < 64)
        sums[t * 64 + k] = part[0][k] + part[1][k] + part[2][k] + part[3][k];
}

// ---- stage 2: ALL means in parallel (range-mean identity) ----
__global__ void r22_means(const float* __restrict__ sums, float* __restrict__ means,
                          float* __restrict__ mn2, float* __restrict__ out) {
    int h = blockIdx.x + 1;
    int k = threadIdx.x;
    int d = 32 - __clz(h);
    int t = h - (1 << (d - 1));
    int lo = t << (8 - d), cnt = 1 << (8 - d);
    float s = 0.f;
    for (int l = lo; l < lo + cnt; ++l) s += sums[l * 64 + k];
    float mv = s / (float)(1 << (17 - d));
    means[blockIdx.x * 64 + k] = mv;
    long long bb = 0;
    for (int jj = 1; jj <= d - 1; ++jj)
        if ((t >> (d - 1 - jj)) & 1) bb += cN[jj + 1];
    out[(bb + cN[d] - 1) * 64 + k] = mv;
    float sq = mv * mv;
    #pragma unroll
    for (int o = 32; o; o >>= 1) sq += __shfl_xor(sq, o, 64);
    if (k == 0) mn2[blockIdx.x] = sq;
}

// ---- stage 3: MAIN fused kernel: leaf | int | idx_int | nodeL | meanpairs ----
__global__ __launch_bounds__(256) void r22_main(const float* __restrict__ X,
                                                const float* __restrict__ means,
                                                const float* __restrict__ mn2,
                                                float* __restrict__ out) {
    __shared__ float As[32][128];
    __shared__ float Bs[32][128];
    int bid = blockIdx.x;
    int tid = threadIdx.x;

    if (bid < MB_LEAF) {
        // ---------------- leaf tiles: vals + idx0 + idx1 ----------------
        int t = bid >> 4, tile = bid & 15, br = tile >> 2, bc = tile & 3;
        long long voff = 0; int nb = 0;
        #pragma unroll
        for (int jj = 1; jj <= 7; ++jj)
            if ((t >> (7 - jj)) & 1) { voff += cV[jj + 1]; nb += cN[jj + 1]; }
        const float* xleaf = X + (long long)t * 32768;

        float acc[8][8] = {};
        float na[8] = {}, nb2[8] = {};
        for (int ks = 0; ks < 64; ks += 32) {
            __syncthreads();
            #pragma unroll
            for (int u = 0; u < 4; ++u) {
                int idx = tid * 4 + u;
                int i = idx >> 3, k4 = (idx & 7) * 4;
                float4 va = *(const float4*)&xleaf[(long long)(br * 128 + i) * 64 + ks + k4];
                As[k4 + 0][i] = va.x; As[k4 + 1][i] = va.y; As[k4 + 2][i] = va.z; As[k4 + 3][i] = va.w;
                float4 vb = *(const float4*)&xleaf[(long long)(bc * 128 + i) * 64 + ks + k4];
                Bs[k4 + 0][i] = vb.x; Bs[k4 + 1][i] = vb.y; Bs[k4 + 2][i] = vb.z; Bs[k4 + 3][i] = vb.w;
            }
            __syncthreads();
            int ty = tid >> 4, tx = tid & 15;
            for (int k = 0; k < 32; ++k) {
                float a[8], bb[8];
                *(float4*)&a[0]  = *(const float4*)&As[k][ty * 8];
                *(float4*)&a[4]  = *(const float4*)&As[k][ty * 8 + 4];
                *(float4*)&bb[0] = *(const float4*)&Bs[k][tx * 4];
                *(float4*)&bb[4] = *(const float4*)&Bs[k][64 + tx * 4];
                #pragma unroll
                for (int r = 0; r < 8; ++r)
                    #pragma unroll
                    for (int c = 0; c < 8; ++c) acc[r][c] += a[r] * bb[c];
                #pragma unroll
                for (int r = 0; r < 8; ++r) na[r] = fmaf(a[r], a[r], na[r]);
                #pragma unroll
                for (int c = 0; c < 8; ++c) nb2[c] = fmaf(bb[c], bb[c], nb2[c]);
            }
        }

        int ty = tid >> 4, tx = tid & 15;
        int r0g = br * 128 + ty * 8;
        int cga = bc * 128 + tx * 4;

        f4a i1q[2];
        #pragma unroll
        for (int c = 0; c < 4; ++c) {
            i1q[0][c] = (float)(nb + cga + c);
            i1q[1][c] = (float)(nb + cga + 64 + c);
        }

        #pragma unroll
        for (int r = 0; r < 8; ++r) {
            int grow = r0g + r;
            float nar = na[r];
            float i0f = (float)(nb + grow);
            f4a i0q = {i0f, i0f, i0f, i0f};
            long long rb = voff + (long long)grow * 512;
            #pragma unroll
            for (int h = 0; h < 2; ++h) {
                long long cb = rb + cga + h * 64;
                f4a vv;
                #pragma unroll
                for (int c = 0; c < 4; ++c) {
                    float d2 = nar + nb2[h * 4 + c] - 2.0f * acc[r][h * 4 + c];
                    vv[c] = __expf(-d2 * 0.015625f);
                }
                *(f4a*)&out[VALS_OFF + cb] = vv;
                *(f4a*)&out[IDX0_OFF + cb] = i0q;
                *(f4a*)&out[IDX1_OFF + cb] = i1q[h];
            }
        }
    } else if (bid < MB_INT) {
        // ---- internal-chunk X-row values: one THREAD per row ----
        int r = ((bid - MB_LEAF) << 8) + tid;
        float4 xv[16];
        const float4* xp = (const float4*)(X + (long long)r * 64);
        #pragma unroll
        for (int i = 0; i < 16; ++i) xv[i] = xp[i];
        float xnr = 0.f;
        #pragma unroll
        for (int i = 0; i < 16; ++i)
            xnr += xv[i].x * xv[i].x + xv[i].y * xv[i].y
                 + xv[i].z * xv[i].z + xv[i].w * xv[i].w;
        int t7 = r >> 9, col = r & 511;
        long long voff = 0;
        #pragma unroll
        for (int d = 1; d <= 7; ++d) {
            int h0 = (1 << (d - 1)) + (r >> (17 - d)) - 1;   // wave-uniform
            const float* mrow = means + h0 * 64;
            float dot = 0.f;
            #pragma unroll
            for (int i = 0; i < 16; ++i)
                dot += xv[i].x * mrow[4 * i] + xv[i].y * mrow[4 * i + 1]
                     + xv[i].z * mrow[4 * i + 2] + xv[i].w * mrow[4 * i + 3];
            long long q = col;
            #pragma unroll
            for (int jj = 1; jj <= 7; ++jj)
                if (jj >= d && ((t7 >> (7 - jj)) & 1)) q += cN[jj + 1];
            long long m = cN[d] - 1;
            long long co = voff + 2 * cV[d + 1];
            float v = __expf(-(xnr - 2.0f * dot + mn2[h0]) * 0.015625f);
            out[VALS_OFF + co + q]     = v;
            out[VALS_OFF + co + m + q] = v;
            if ((t7 >> (7 - d)) & 1) voff += cV[d + 1];
        }
    } else if (bid < MB_IDXI) {
        // ---- internal-chunk indices ----
        int local = bid - MB_INT;
        int d = local / 514 + 1;
        int bx = local % 514;
        int sz = cSZ[d];
        int m = cN[d] - 1;
        long long pos = (long long)bx * 256 + tid;
        long long tot = (long long)(1 << (d - 1)) * sz;
        if (pos < tot) {
            int t = (int)(pos / sz);
            int e = (int)(pos % sz);
            long long voff = 0; long long base = 0;
            for (int jj = 1; jj < d; ++jj)
                if ((t >> (d - 1 - jj)) & 1) { voff += cV[jj + 1]; base += cN[jj + 1]; }
            long long p = voff + 2 * cV[d + 1] + e;
            long long i0, i1;
            if (e < m)          { i0 = base + e;     i1 = base + m; }
            else if (e < 2 * m) { i0 = base + m;     i1 = base + e - m; }
            else                { i0 = base + m;     i1 = base + m; }
            out[IDX0_OFF + p] = (float)i0;
            out[IDX1_OFF + p] = (float)i1;
        }
    } else if (bid < MB_NODEL) {
        // ---- leaf-node rows ----
        int local = bid - MB_IDXI;
        long long e = ((long long)local * 256 + tid) * 4;
        int t = (int)(e >> 15);
        int l = (int)(e & 32767);
        int j = l >> 6, k = l & 63;
        int b = 0;
        #pragma unroll
        for (int jj = 1; jj <= 7; ++jj) if ((t >> (7 - jj)) & 1) b += cN[jj + 1];
        float4 v = *(const float4*)&X[e];
        *(float4*)&out[((long long)b + j) * 64 + k] = v;
    } else {
        // ---- mean-vs-mean pairs + 1.0 entries ----
        int local = bid - MB_NODEL;
        int wv = (local << 2) + (tid >> 6);
        int lane = tid & 63;
        if (wv >= 769) return;
        if (wv < 642) {
            int g = 0;
            while (g < 20 && wv >= gB[g + 1]) ++g;
            int dp = gD[g], a = gA[g];
            int tp = wv - gB[g];
            int hp = (1 << (dp - 1)) + tp;
            int ha = hp >> (dp - a);
            float da = means[(hp - 1) * 64 + lane] - means[(ha - 1) * 64 + lane];
            float s = da * da;
            #pragma unroll
            for (int o = 32; o; o >>= 1) s += __shfl_xor(s, o, 64);
            if (lane == 0) {
                float v = __expf(-s * 0.015625f);
                int ta = ha - (1 << (a - 1));
                long long voff = 0;
                for (int jj = 1; jj <= a - 1; ++jj)
                    if ((ta >> (a - 1 - jj)) & 1) voff += cV[jj + 1];
                long long q = cN[dp] - 1;
                for (int jj = a; jj <= dp - 1; ++jj)
                    if ((tp >> (dp - 1 - jj)) & 1) q += cN[jj + 1];
                long long m = cN[a] - 1;
                long long co = voff + 2 * cV[a + 1];
                out[VALS_OFF + co + q]     = v;
                out[VALS_OFF + co + m + q] = v;
            }
        } else if (lane == 0) {
            int h = wv - 642 + 1;
            int d = 32 - __clz(h);
            int t = h - (1 << (d - 1));
            long long voff = 0;
            for (int jj = 1; jj <= d - 1; ++jj)
                if ((t >> (d - 1 - jj)) & 1) voff += cV[jj + 1];
            long long m = cN[d] - 1;
            out[VALS_OFF + voff + 2 * cV[d + 1] + 2 * m] = 1.0f;
        }
    }
}

extern "C" void kernel_launch(void* const* d_in, const int* in_sizes, int n_in,
                              void* d_out, int out_size, void* d_ws, size_t ws_size,
                              hipStream_t stream) {
    const float* X = (const float*)d_in[0];
    float* out = (float*)d_out;

    float* sums  = (float*)d_ws;              // 128*64
    float* means = sums + 128 * 64;           // 127*64
    float* mn2   = means + 127 * 64;          // 127

    if (out_size != (int)OUT_TOTAL) return;
    if (ws_size < (size_t)(128 * 64 + 127 * 64 + 128) * sizeof(float)) return;

    r22_sums <<<128,    256, 0, stream>>>(X, sums);
    r22_means<<<127,     64, 0, stream>>>(sums, means, mn2, out);
    r22_main <<<MB_ALL, 256, 0, stream>>>(X, means, mn2, out);
}